// Round 5
// baseline (1038.519 us; speedup 1.0000x reference)
//
#include <hip/hip_runtime.h>

// FiLM LSTM via multi-batch MFMA:
//   16 blocks x 256 threads (4 waves). Each block owns 16 batches.
//   Per step: Z[16x256] = [H | X_t][16x128] @ [U ; W][128x256] + bias
//   using v_mfma_f32_16x16x32_f16 (4 K-frags x 4 N-tiles per wave).
//   Wave w owns N-tiles {w, 4+w, 8+w, 12+w} = gates i,f,g,o of units
//   [16w,16w+16): all 4 gates of a unit land in the same lane (cols mod 16),
//   so the cell update is lane-local; c,h live in VGPRs (4 per lane).
//   h exchanged via double-buffered XOR-swizzled LDS; ONE barrier per step.
//   X A-frags loaded from global f32, 2-step register prefetch.

typedef _Float16 f16;
typedef f16  half8 __attribute__((ext_vector_type(8)));
typedef float f32x4 __attribute__((ext_vector_type(4)));

constexpr int Bsz = 256;
constexpr int Tn  = 2048;
constexpr int Dn  = 64;
constexpr int Hn  = 64;
constexpr int G4  = 256;          // 4*H
constexpr int BPB = 16;           // batches per block

__device__ __forceinline__ float sigmoidf_fast(float z) {
    return __builtin_amdgcn_rcpf(1.0f + __expf(-z));
}

// swizzled byte address of h element (batch b, byte offset within 128B row)
__device__ __forceinline__ int haddr(int b, int byte_in_row) {
    return (b * 128 + byte_in_row) ^ ((b & 7) << 4);
}

__global__ __launch_bounds__(256, 1) void lstm_film_mfma(
    const float* __restrict__ x,     // [B,T,64]
    const float* __restrict__ W,     // [64,256]
    const float* __restrict__ U,     // [64,256]
    const float* __restrict__ bias,  // [256]
    const float* __restrict__ wg, const float* __restrict__ bgam,
    const float* __restrict__ wb, const float* __restrict__ bbet,
    float* __restrict__ out)         // gamma[256] then beta[256]
{
    __shared__ __align__(16) f16 hbuf[2][BPB * Hn];   // 2 x 2KB, swizzled

    const int tid  = threadIdx.x;
    const int w    = tid >> 6;        // wave 0..3
    const int l    = tid & 63;        // lane
    const int lrow = l & 15;          // A-row / C-col index
    const int kgrp = l >> 4;          // 0..3

    // ---- B fragments: Bf[kf][q], kf: 0,1 = U rows 0-31/32-63; 2,3 = W ----
    // B[k][col]: lane supplies k = kf*32 + kgrp*8 + j, col = 64*q + 16*w + lrow
    half8 Bf[4][4];
#pragma unroll
    for (int kf = 0; kf < 4; ++kf) {
        const float* M = (kf < 2) ? U : W;
        const int krow0 = (kf & 1) * 32 + kgrp * 8;
#pragma unroll
        for (int q = 0; q < 4; ++q) {
            const int col = q * 64 + w * 16 + lrow;
#pragma unroll
            for (int j = 0; j < 8; ++j)
                Bf[kf][q][j] = (f16)M[(krow0 + j) * G4 + col];
        }
    }
    // bias per tile (same for all 4 C-rows of this lane)
    float bq[4];
#pragma unroll
    for (int q = 0; q < 4; ++q) bq[q] = bias[q * 64 + w * 16 + lrow];

    // ---- init h buffers to zero (t=0 reads hbuf[0]) and c ----
    ((uint4*)hbuf)[tid] = uint4{0, 0, 0, 0};   // 256 x 16B = 4KB = both bufs
    float c0 = 0.f, c1 = 0.f, c2 = 0.f, c3 = 0.f;

    // ---- x addressing: lane covers batch=lrow, x cols kgrp*8..+7 (+32) ----
    const float* xlane = x + ((size_t)(blockIdx.x * BPB + lrow) * Tn) * Dn + kgrp * 8;

    // h-frag LDS byte addresses (swizzled; XOR keeps 16B blocks intact)
    const int rdA = haddr(lrow, kgrp * 16);        // k 0..31 slice
    const int rdB = haddr(lrow, kgrp * 16 + 64);   // k 32..63 slice
    // h write addresses: rows = batches kgrp*4+r, unit u = 16w + lrow
    const int wr0 = haddr(kgrp * 4 + 0, (w * 16 + lrow) * 2);
    const int wr1 = haddr(kgrp * 4 + 1, (w * 16 + lrow) * 2);
    const int wr2 = haddr(kgrp * 4 + 2, (w * 16 + lrow) * 2);
    const int wr3 = haddr(kgrp * 4 + 3, (w * 16 + lrow) * 2);

    __syncthreads();   // hbuf cleared

#define XLOAD(dst, T) do {                                                   \
        const float* p_ = xlane + (size_t)(T) * Dn;                          \
        dst[0] = *(const float4*)(p_);                                       \
        dst[1] = *(const float4*)(p_ + 4);                                   \
        dst[2] = *(const float4*)(p_ + 32);                                  \
        dst[3] = *(const float4*)(p_ + 36);                                  \
    } while (0)

    float4 ldA[4], ldB[4];
    XLOAD(ldA, 0);
    XLOAD(ldB, 1);

#define STEP(LD, PBUF, TNEXT) do {                                           \
        const f16* hb = hbuf[PBUF];                                          \
        half8 ah0 = *(const half8*)((const char*)hb + rdA);                  \
        half8 ah1 = *(const half8*)((const char*)hb + rdB);                  \
        half8 ax0, ax1;                                                      \
        ax0[0]=(f16)LD[0].x; ax0[1]=(f16)LD[0].y; ax0[2]=(f16)LD[0].z;       \
        ax0[3]=(f16)LD[0].w; ax0[4]=(f16)LD[1].x; ax0[5]=(f16)LD[1].y;       \
        ax0[6]=(f16)LD[1].z; ax0[7]=(f16)LD[1].w;                            \
        ax1[0]=(f16)LD[2].x; ax1[1]=(f16)LD[2].y; ax1[2]=(f16)LD[2].z;       \
        ax1[3]=(f16)LD[2].w; ax1[4]=(f16)LD[3].x; ax1[5]=(f16)LD[3].y;       \
        ax1[6]=(f16)LD[3].z; ax1[7]=(f16)LD[3].w;                            \
        XLOAD(LD, TNEXT);                                                    \
        f32x4 z0 = {bq[0], bq[0], bq[0], bq[0]};                             \
        f32x4 z1 = {bq[1], bq[1], bq[1], bq[1]};                             \
        f32x4 z2 = {bq[2], bq[2], bq[2], bq[2]};                             \
        f32x4 z3 = {bq[3], bq[3], bq[3], bq[3]};                             \
        z0 = __builtin_amdgcn_mfma_f32_16x16x32_f16(ah0, Bf[0][0], z0,0,0,0);\
        z1 = __builtin_amdgcn_mfma_f32_16x16x32_f16(ah0, Bf[0][1], z1,0,0,0);\
        z2 = __builtin_amdgcn_mfma_f32_16x16x32_f16(ah0, Bf[0][2], z2,0,0,0);\
        z3 = __builtin_amdgcn_mfma_f32_16x16x32_f16(ah0, Bf[0][3], z3,0,0,0);\
        z0 = __builtin_amdgcn_mfma_f32_16x16x32_f16(ah1, Bf[1][0], z0,0,0,0);\
        z1 = __builtin_amdgcn_mfma_f32_16x16x32_f16(ah1, Bf[1][1], z1,0,0,0);\
        z2 = __builtin_amdgcn_mfma_f32_16x16x32_f16(ah1, Bf[1][2], z2,0,0,0);\
        z3 = __builtin_amdgcn_mfma_f32_16x16x32_f16(ah1, Bf[1][3], z3,0,0,0);\
        z0 = __builtin_amdgcn_mfma_f32_16x16x32_f16(ax0, Bf[2][0], z0,0,0,0);\
        z1 = __builtin_amdgcn_mfma_f32_16x16x32_f16(ax0, Bf[2][1], z1,0,0,0);\
        z2 = __builtin_amdgcn_mfma_f32_16x16x32_f16(ax0, Bf[2][2], z2,0,0,0);\
        z3 = __builtin_amdgcn_mfma_f32_16x16x32_f16(ax0, Bf[2][3], z3,0,0,0);\
        z0 = __builtin_amdgcn_mfma_f32_16x16x32_f16(ax1, Bf[3][0], z0,0,0,0);\
        z1 = __builtin_amdgcn_mfma_f32_16x16x32_f16(ax1, Bf[3][1], z1,0,0,0);\
        z2 = __builtin_amdgcn_mfma_f32_16x16x32_f16(ax1, Bf[3][2], z2,0,0,0);\
        z3 = __builtin_amdgcn_mfma_f32_16x16x32_f16(ax1, Bf[3][3], z3,0,0,0);\
        f16* ho = hbuf[(PBUF) ^ 1];                                          \
        {                                                                    \
            float gi, gf, gg, go, hh;                                        \
            gi = sigmoidf_fast(z0[0]); gf = sigmoidf_fast(z1[0]);            \
            gg = sigmoidf_fast(z2[0]); go = sigmoidf_fast(z3[0]);            \
            c0 = fmaf(gf, c0, gi * gg); hh = go * sigmoidf_fast(c0);         \
            *(f16*)((char*)ho + wr0) = (f16)hh;                              \
            gi = sigmoidf_fast(z0[1]); gf = sigmoidf_fast(z1[1]);            \
            gg = sigmoidf_fast(z2[1]); go = sigmoidf_fast(z3[1]);            \
            c1 = fmaf(gf, c1, gi * gg); hh = go * sigmoidf_fast(c1);         \
            *(f16*)((char*)ho + wr1) = (f16)hh;                              \
            gi = sigmoidf_fast(z0[2]); gf = sigmoidf_fast(z1[2]);            \
            gg = sigmoidf_fast(z2[2]); go = sigmoidf_fast(z3[2]);            \
            c2 = fmaf(gf, c2, gi * gg); hh = go * sigmoidf_fast(c2);         \
            *(f16*)((char*)ho + wr2) = (f16)hh;                              \
            gi = sigmoidf_fast(z0[3]); gf = sigmoidf_fast(z1[3]);            \
            gg = sigmoidf_fast(z2[3]); go = sigmoidf_fast(z3[3]);            \
            c3 = fmaf(gf, c3, gi * gg); hh = go * sigmoidf_fast(c3);         \
            *(f16*)((char*)ho + wr3) = (f16)hh;                              \
        }                                                                    \
        __syncthreads();                                                     \
    } while (0)

    for (int t = 0; t < Tn; t += 2) {
        const int tA = t + 2 < Tn ? t + 2 : Tn - 1;
        const int tB = t + 3 < Tn ? t + 3 : Tn - 1;
        STEP(ldA, 0, tA);   // even step reads hbuf[0], writes hbuf[1]
        STEP(ldB, 1, tB);   // odd step reads hbuf[1], writes hbuf[0]
    }
#undef STEP
#undef XLOAD

    // ---- heads: final h in hbuf[0]; wave w reduces batches 4w..4w+3 ----
    const float wgj = wg[l], wbj = wb[l];
#pragma unroll
    for (int r = 0; r < 4; ++r) {
        const int b = w * 4 + r;
        float hv = (float)*(const f16*)((const char*)hbuf[0] + haddr(b, l * 2));
        float vg = hv * wgj, vb = hv * wbj;
#pragma unroll
        for (int off = 32; off > 0; off >>= 1) {
            vg += __shfl_xor(vg, off, 64);
            vb += __shfl_xor(vb, off, 64);
        }
        if (l == 0) {
            out[blockIdx.x * BPB + b]       = vg + bgam[0];
            out[Bsz + blockIdx.x * BPB + b] = vb + bbet[0];
        }
    }
}

extern "C" void kernel_launch(void* const* d_in, const int* in_sizes, int n_in,
                              void* d_out, int out_size, void* d_ws, size_t ws_size,
                              hipStream_t stream) {
    const float* x    = (const float*)d_in[0];
    const float* W    = (const float*)d_in[2];
    const float* U    = (const float*)d_in[3];
    const float* bias = (const float*)d_in[4];
    const float* wg   = (const float*)d_in[5];
    const float* bgam = (const float*)d_in[6];
    const float* wb   = (const float*)d_in[7];
    const float* bbet = (const float*)d_in[8];
    float* out = (float*)d_out;

    lstm_film_mfma<<<Bsz / BPB, 256, 0, stream>>>(x, W, U, bias,
                                                  wg, bgam, wb, bbet, out);
}